// Round 5
// baseline (1111.607 us; speedup 1.0000x reference)
//
#include <hip/hip_runtime.h>
#include <hip/hip_bf16.h>
#include <math.h>

#define NBLK 64          // 1024 rows / 16 rows-per-block
#define NTHR 512         // 8 waves; wave wv owns feature tile wv (16 feats)
#define TPTS 96
#define CTOT 128
#define LDP 134          // LDS row pitch u16 (67 dwords): <=2-way banks (verified R4)

typedef __bf16 bf16x8_t __attribute__((ext_vector_type(8)));
typedef float f32x4_t __attribute__((ext_vector_type(4)));
typedef unsigned short us8_t __attribute__((ext_vector_type(8)));

// raw barrier: LDS visibility only, leaves global stores in flight (no vmcnt drain)
#define BAR() asm volatile("s_waitcnt lgkmcnt(0)\n\ts_barrier" ::: "memory")

__device__ __forceinline__ unsigned short f2b(float f) {
    union { float f; unsigned int i; } v; v.f = f;
    unsigned int r = v.i + 0x7fffu + ((v.i >> 16) & 1u);
    return (unsigned short)(r >> 16);
}
__device__ __forceinline__ float u2f_lo(unsigned int w) {
    union { unsigned int i; float f; } v; v.i = w << 16; return v.f;
}
__device__ __forceinline__ float u2f_hi(unsigned int w) {
    union { unsigned int i; float f; } v; v.i = w & 0xffff0000u; return v.f;
}
__device__ __forceinline__ f32x4_t mfma16(bf16x8_t a, bf16x8_t b, f32x4_t c) {
    return __builtin_amdgcn_mfma_f32_16x16x32_bf16(a, b, c, 0, 0, 0);
}
__device__ __forceinline__ bf16x8_t ldfrag(const unsigned short* p) {
    us8_t v = *(const us8_t*)p;
    return __builtin_bit_cast(bf16x8_t, v);
}
__device__ __forceinline__ bf16x8_t ldfragW(const float* p) {
    float4 a = *(const float4*)p;
    float4 b = *(const float4*)(p + 4);
    bf16x8_t r;
    r[0] = __builtin_bit_cast(__bf16, f2b(a.x)); r[1] = __builtin_bit_cast(__bf16, f2b(a.y));
    r[2] = __builtin_bit_cast(__bf16, f2b(a.z)); r[3] = __builtin_bit_cast(__bf16, f2b(a.w));
    r[4] = __builtin_bit_cast(__bf16, f2b(b.x)); r[5] = __builtin_bit_cast(__bf16, f2b(b.y));
    r[6] = __builtin_bit_cast(__bf16, f2b(b.z)); r[7] = __builtin_bit_cast(__bf16, f2b(b.w));
    return r;
}
__device__ __forceinline__ uint2 pack4(float v0, float v1, float v2, float v3) {
    uint2 w;
    w.x = (unsigned int)f2b(v0) | ((unsigned int)f2b(v1) << 16);
    w.y = (unsigned int)f2b(v2) | ((unsigned int)f2b(v3) << 16);
    return w;
}
// tanh(x) = 1 - 2/(e^{2x}+1); IEEE-safe at +/-inf, no clamps (x always finite here)
__device__ __forceinline__ float tanh2(float x) {
    float e = __expf(x + x);
    return 1.f - __fdividef(2.f, e + 1.f);
}
__device__ __forceinline__ float sigm(float x) {
    return __fdividef(1.f, 1.f + __expf(-x));
}

// Transposed MFMA formulation (verified R2-R4): D = W * S^T, C-layout:
// row(out-feat) = quad*4+i, col(batch-row) = lane&15.
// Serial-path minimization: GRU input-gates gi0/gi1 are bulk-computed (fused into
// the producing phase, off the recurrence critical path) and staged in ws (bf16).
__global__ void __launch_bounds__(NTHR, 2)
ode_forecaster(const float* __restrict__ yl,
               const float* __restrict__ yh,
               const float* __restrict__ Wode,
               const float* __restrict__ bode,
               const float* __restrict__ Wih0,
               const float* __restrict__ Whh0,
               const float* __restrict__ bih0,
               const float* __restrict__ bhh0,
               const float* __restrict__ Wih1,
               const float* __restrict__ Whh1,
               const float* __restrict__ bih1,
               const float* __restrict__ bhh1,
               const float* __restrict__ W1v,
               const float* __restrict__ b1v,
               const float* __restrict__ W2v,
               const float* __restrict__ b2v,
               float* __restrict__ outp,
               uint2* __restrict__ ws)
{
    const int tid   = threadIdx.x;
    const int lane  = tid & 63;
    const int wv    = tid >> 6;        // 0..7
    const int l15   = lane & 15;       // batch-row within block
    const int quad  = lane >> 4;       // 0..3
    const int rbase = blockIdx.x * 16;
    const int fbase = wv * 16 + quad * 4;   // this lane's 4 output feats

    __shared__ __align__(16) unsigned short zbuf[2][16][LDP];
    __shared__ __align__(16) unsigned short hidbuf[16][72];

    // gi layout in ws (uint2 = 4 bf16): [t][wv][g][lane]; per-block 96*8*3*64 u2
    const int PBLK = 96 * 8 * 3 * 64;                       // 147456 u2 per block
    uint2* gi0 = ws + (size_t)blockIdx.x * PBLK;
    uint2* gi1 = ws + (size_t)NBLK * PBLK + (size_t)blockIdx.x * PBLK;
#define GI(t, g) ((size_t)(t) * 1536 + (wv * 3 + (g)) * 64 + lane)

    // ---------------- phase weights: ODE = Wode + Wih0 (A-frags) --------------
    bf16x8_t wode[4], wih0[3][4];
#pragma unroll
    for (int kt = 0; kt < 4; ++kt)
        wode[kt] = ldfragW(Wode + (wv * 16 + l15) * CTOT + kt * 32 + quad * 8);
#pragma unroll
    for (int g = 0; g < 3; ++g)
#pragma unroll
        for (int kt = 0; kt < 4; ++kt)
            wih0[g][kt] = ldfragW(Wih0 + (g * 128 + wv * 16 + l15) * CTOT + kt * 32 + quad * 8);
    float bo[4];
    {
        float4 b4 = *(const float4*)(bode + fbase);
        bo[0] = b4.x; bo[1] = b4.y; bo[2] = b4.z; bo[3] = b4.w;
    }

    // ---------------- init y0 -------------------------------------------------
    float y[4];
    {
        int row = rbase + l15;
#pragma unroll
        for (int i = 0; i < 4; ++i) {
            int f = fbase + i;
            y[i] = (f < 32) ? yl[row * 32 + f] : yh[row * 96 + (f - 32)];
        }
        *(uint2*)&zbuf[0][l15][fbase] = pack4(y[0], y[1], y[2], y[3]);
    }
    __syncthreads();

    // ---------------- ODE: 95 dopri5 steps (+ fused gi0) ----------------------
    const float dt = 1.0f / 95.0f;
    const float B1 = 35.f / 384.f, B3 = 500.f / 1113.f, B4 = 125.f / 192.f,
                B5 = -2187.f / 6784.f, B6 = 11.f / 84.f;

    int p = 0;
    float kr[6][4];
#pragma unroll 1
    for (int t = 0; t < 95; ++t) {
#pragma unroll
        for (int s = 0; s < 6; ++s) {
            bf16x8_t bf[4];
#pragma unroll
            for (int kt = 0; kt < 4; ++kt)
                bf[kt] = ldfrag(&zbuf[p][l15][kt * 32 + quad * 8]);
            f32x4_t acc = {0.f, 0.f, 0.f, 0.f};
#pragma unroll
            for (int kt = 0; kt < 4; ++kt) acc = mfma16(wode[kt], bf[kt], acc);

            f32x4_t gacc[3];
            if (s == 0) {   // fused gi0[t] = Wih0 * y_t (off critical path)
#pragma unroll
                for (int g = 0; g < 3; ++g) {
                    f32x4_t a = {0.f, 0.f, 0.f, 0.f};
#pragma unroll
                    for (int kt = 0; kt < 4; ++kt) a = mfma16(wih0[g][kt], bf[kt], a);
                    gacc[g] = a;
                }
            }
#pragma unroll
            for (int i = 0; i < 4; ++i) kr[s][i] = tanh2(acc[i] + bo[i]);

            if (s < 5) {
                float z[4];
#pragma unroll
                for (int i = 0; i < 4; ++i) {
                    float zv;
                    if (s == 0)      zv = 0.2f * kr[0][i];
                    else if (s == 1) zv = (3.f/40.f)*kr[0][i] + (9.f/40.f)*kr[1][i];
                    else if (s == 2) zv = (44.f/45.f)*kr[0][i] + (-56.f/15.f)*kr[1][i] + (32.f/9.f)*kr[2][i];
                    else if (s == 3) zv = (19372.f/6561.f)*kr[0][i] + (-25360.f/2187.f)*kr[1][i]
                                        + (64448.f/6561.f)*kr[2][i] + (-212.f/729.f)*kr[3][i];
                    else             zv = (9017.f/3168.f)*kr[0][i] + (-355.f/33.f)*kr[1][i]
                                        + (46732.f/5247.f)*kr[2][i] + (49.f/176.f)*kr[3][i]
                                        + (-5103.f/18656.f)*kr[4][i];
                    z[i] = y[i] + dt * zv;
                }
                *(uint2*)&zbuf[p ^ 1][l15][fbase] = pack4(z[0], z[1], z[2], z[3]);
            } else {
#pragma unroll
                for (int i = 0; i < 4; ++i) {
                    float fc = B1*kr[0][i] + B3*kr[2][i] + B4*kr[3][i] + B5*kr[4][i] + B6*kr[5][i];
                    y[i] += dt * fc;
                }
                *(uint2*)&zbuf[p ^ 1][l15][fbase] = pack4(y[0], y[1], y[2], y[3]);
            }
            if (s == 0) {
#pragma unroll
                for (int g = 0; g < 3; ++g)
                    gi0[GI(t, g)] = pack4(gacc[g][0], gacc[g][1], gacc[g][2], gacc[g][3]);
            }
            BAR();
            p ^= 1;
        }
    }
    // gi0[95] from y_95 (in zbuf[p])
    {
        bf16x8_t bf[4];
#pragma unroll
        for (int kt = 0; kt < 4; ++kt)
            bf[kt] = ldfrag(&zbuf[p][l15][kt * 32 + quad * 8]);
#pragma unroll
        for (int g = 0; g < 3; ++g) {
            f32x4_t a = {0.f, 0.f, 0.f, 0.f};
#pragma unroll
            for (int kt = 0; kt < 4; ++kt) a = mfma16(wih0[g][kt], bf[kt], a);
            gi0[GI(95, g)] = pack4(a[0], a[1], a[2], a[3]);
        }
    }
    __syncthreads();   // full drain: own gi0 stores ack'd before GRU0 reads

    // ---------------- GRU0: h-recurrence + fused gi1 --------------------------
    float h[4];
    {
        bf16x8_t whh[3][4], wnx[3][4];
#pragma unroll
        for (int g = 0; g < 3; ++g)
#pragma unroll
            for (int kt = 0; kt < 4; ++kt) {
                whh[g][kt] = ldfragW(Whh0 + (g * 128 + wv * 16 + l15) * CTOT + kt * 32 + quad * 8);
                wnx[g][kt] = ldfragW(Wih1 + (g * 128 + wv * 16 + l15) * CTOT + kt * 32 + quad * 8);
            }
        float bi[3][4], bh[3][4];
#pragma unroll
        for (int g = 0; g < 3; ++g) {
            float4 a = *(const float4*)(bih0 + g * 128 + fbase);
            float4 b = *(const float4*)(bhh0 + g * 128 + fbase);
            bi[g][0] = a.x; bi[g][1] = a.y; bi[g][2] = a.z; bi[g][3] = a.w;
            bh[g][0] = b.x; bh[g][1] = b.y; bh[g][2] = b.z; bh[g][3] = b.w;
        }
#pragma unroll
        for (int i = 0; i < 4; ++i) h[i] = 0.f;
        *(uint2*)&zbuf[0][l15][fbase] = pack4(0.f, 0.f, 0.f, 0.f);
        p = 0;
        __syncthreads();

        uint2 gA[3], gB[3];
#pragma unroll
        for (int g = 0; g < 3; ++g) { gA[g] = gi0[GI(0, g)]; gB[g] = gi0[GI(1, g)]; }

#pragma unroll 1
        for (int t = 0; t < TPTS; ++t) {
            uint2 gC[3];
            if (t + 2 < TPTS) {
#pragma unroll
                for (int g = 0; g < 3; ++g) gC[g] = gi0[GI(t + 2, g)];
            }
            bf16x8_t ah[4];
#pragma unroll
            for (int kt = 0; kt < 4; ++kt)
                ah[kt] = ldfrag(&zbuf[p][l15][kt * 32 + quad * 8]);

            f32x4_t gh[3], gx[3];
#pragma unroll
            for (int g = 0; g < 3; ++g) {
                gh[g] = (f32x4_t){0.f, 0.f, 0.f, 0.f};
                gx[g] = (f32x4_t){0.f, 0.f, 0.f, 0.f};
            }
#pragma unroll
            for (int kt = 0; kt < 4; ++kt) {
                gh[0] = mfma16(whh[0][kt], ah[kt], gh[0]);
                gh[1] = mfma16(whh[1][kt], ah[kt], gh[1]);
                gh[2] = mfma16(whh[2][kt], ah[kt], gh[2]);
                gx[0] = mfma16(wnx[0][kt], ah[kt], gx[0]);   // fused gi1[t-1]
                gx[1] = mfma16(wnx[1][kt], ah[kt], gx[1]);
                gx[2] = mfma16(wnx[2][kt], ah[kt], gx[2]);
            }
            float gr[3][4];
#pragma unroll
            for (int g = 0; g < 3; ++g) {
                gr[g][0] = u2f_lo(gA[g].x); gr[g][1] = u2f_hi(gA[g].x);
                gr[g][2] = u2f_lo(gA[g].y); gr[g][3] = u2f_hi(gA[g].y);
            }
#pragma unroll
            for (int i = 0; i < 4; ++i) {
                float rr = sigm((gr[0][i] + bi[0][i]) + (gh[0][i] + bh[0][i]));
                float zz = sigm((gr[1][i] + bi[1][i]) + (gh[1][i] + bh[1][i]));
                float nn = tanh2((gr[2][i] + bi[2][i]) + rr * (gh[2][i] + bh[2][i]));
                h[i] = (1.f - zz) * nn + zz * h[i];
            }
            *(uint2*)&zbuf[p ^ 1][l15][fbase] = pack4(h[0], h[1], h[2], h[3]);
            if (t > 0) {
#pragma unroll
                for (int g = 0; g < 3; ++g)
                    gi1[GI(t - 1, g)] = pack4(gx[g][0], gx[g][1], gx[g][2], gx[g][3]);
            }
            BAR();
            p ^= 1;
#pragma unroll
            for (int g = 0; g < 3; ++g) { gA[g] = gB[g]; gB[g] = gC[g]; }
        }
        // gi1[95] from h1_95 (in zbuf[p])
        bf16x8_t ah[4];
#pragma unroll
        for (int kt = 0; kt < 4; ++kt)
            ah[kt] = ldfrag(&zbuf[p][l15][kt * 32 + quad * 8]);
#pragma unroll
        for (int g = 0; g < 3; ++g) {
            f32x4_t a = {0.f, 0.f, 0.f, 0.f};
#pragma unroll
            for (int kt = 0; kt < 4; ++kt) a = mfma16(wnx[g][kt], ah[kt], a);
            gi1[GI(95, g)] = pack4(a[0], a[1], a[2], a[3]);
        }
    }
    __syncthreads();   // full drain: own gi1 stores ack'd before GRU1 reads

    // ---------------- GRU1: h-recurrence only ---------------------------------
    {
        bf16x8_t whh[3][4];
#pragma unroll
        for (int g = 0; g < 3; ++g)
#pragma unroll
            for (int kt = 0; kt < 4; ++kt)
                whh[g][kt] = ldfragW(Whh1 + (g * 128 + wv * 16 + l15) * CTOT + kt * 32 + quad * 8);
        float bi[3][4], bh[3][4];
#pragma unroll
        for (int g = 0; g < 3; ++g) {
            float4 a = *(const float4*)(bih1 + g * 128 + fbase);
            float4 b = *(const float4*)(bhh1 + g * 128 + fbase);
            bi[g][0] = a.x; bi[g][1] = a.y; bi[g][2] = a.z; bi[g][3] = a.w;
            bh[g][0] = b.x; bh[g][1] = b.y; bh[g][2] = b.z; bh[g][3] = b.w;
        }
#pragma unroll
        for (int i = 0; i < 4; ++i) h[i] = 0.f;
        *(uint2*)&zbuf[0][l15][fbase] = pack4(0.f, 0.f, 0.f, 0.f);
        p = 0;
        __syncthreads();

        uint2 gA[3], gB[3];
#pragma unroll
        for (int g = 0; g < 3; ++g) { gA[g] = gi1[GI(0, g)]; gB[g] = gi1[GI(1, g)]; }

#pragma unroll 1
        for (int t = 0; t < TPTS; ++t) {
            uint2 gC[3];
            if (t + 2 < TPTS) {
#pragma unroll
                for (int g = 0; g < 3; ++g) gC[g] = gi1[GI(t + 2, g)];
            }
            bf16x8_t ah[4];
#pragma unroll
            for (int kt = 0; kt < 4; ++kt)
                ah[kt] = ldfrag(&zbuf[p][l15][kt * 32 + quad * 8]);
            f32x4_t gh[3];
#pragma unroll
            for (int g = 0; g < 3; ++g) gh[g] = (f32x4_t){0.f, 0.f, 0.f, 0.f};
#pragma unroll
            for (int kt = 0; kt < 4; ++kt) {
                gh[0] = mfma16(whh[0][kt], ah[kt], gh[0]);
                gh[1] = mfma16(whh[1][kt], ah[kt], gh[1]);
                gh[2] = mfma16(whh[2][kt], ah[kt], gh[2]);
            }
            float gr[3][4];
#pragma unroll
            for (int g = 0; g < 3; ++g) {
                gr[g][0] = u2f_lo(gA[g].x); gr[g][1] = u2f_hi(gA[g].x);
                gr[g][2] = u2f_lo(gA[g].y); gr[g][3] = u2f_hi(gA[g].y);
            }
#pragma unroll
            for (int i = 0; i < 4; ++i) {
                float rr = sigm((gr[0][i] + bi[0][i]) + (gh[0][i] + bh[0][i]));
                float zz = sigm((gr[1][i] + bi[1][i]) + (gh[1][i] + bh[1][i]));
                float nn = tanh2((gr[2][i] + bi[2][i]) + rr * (gh[2][i] + bh[2][i]));
                h[i] = (1.f - zz) * nn + zz * h[i];
            }
            *(uint2*)&zbuf[p ^ 1][l15][fbase] = pack4(h[0], h[1], h[2], h[3]);
            BAR();
            p ^= 1;
#pragma unroll
            for (int g = 0; g < 3; ++g) { gA[g] = gB[g]; gB[g] = gC[g]; }
        }
    }
    // zbuf[p] holds h2_95 (bf16)

    // ---------------- MLP head ------------------------------------------------
    if (wv < 4) {
        bf16x8_t bw[4], bh2[4];
#pragma unroll
        for (int kt = 0; kt < 4; ++kt) {
            bw[kt]  = ldfragW(W1v + (wv * 16 + l15) * CTOT + kt * 32 + quad * 8);
            bh2[kt] = ldfrag(&zbuf[p][l15][kt * 32 + quad * 8]);
        }
        f32x4_t acc = {0.f, 0.f, 0.f, 0.f};
#pragma unroll
        for (int kt = 0; kt < 4; ++kt) acc = mfma16(bw[kt], bh2[kt], acc);
        const float4 bb = *(const float4*)(b1v + wv * 16 + quad * 4);
        const float* bbp = (const float*)&bb;
        float gl[4];
#pragma unroll
        for (int i = 0; i < 4; ++i) {
            float x = acc[i] + bbp[i];
            gl[i] = 0.5f * x * (1.0f + erff(x * 0.70710678118654752f));
        }
        *(uint2*)&hidbuf[l15][wv * 16 + quad * 4] = pack4(gl[0], gl[1], gl[2], gl[3]);
    }
    __syncthreads();

    // pred^T = W2 * hidden^T; 24 m-tiles per wave
    bf16x8_t ahid[2];
#pragma unroll
    for (int kt = 0; kt < 2; ++kt)
        ahid[kt] = ldfrag(&hidbuf[l15][kt * 32 + quad * 8]);
#pragma unroll 1
    for (int j = 0; j < 24; ++j) {
        int mt2 = wv * 24 + j;            // output feat tile 0..191
        bf16x8_t wf0 = ldfragW(W2v + (mt2 * 16 + l15) * 64 + quad * 8);
        bf16x8_t wf1 = ldfragW(W2v + (mt2 * 16 + l15) * 64 + 32 + quad * 8);
        const float4 bv = *(const float4*)(b2v + mt2 * 16 + quad * 4);
        const float* bvp = (const float*)&bv;
        f32x4_t acc = {0.f, 0.f, 0.f, 0.f};
        acc = mfma16(wf0, ahid[0], acc);
        acc = mfma16(wf1, ahid[1], acc);
        float4 o;
        o.x = acc[0] + bvp[0]; o.y = acc[1] + bvp[1];
        o.z = acc[2] + bvp[2]; o.w = acc[3] + bvp[3];
        *(float4*)(outp + (size_t)(rbase + l15) * 3072 + mt2 * 16 + quad * 4) = o;
    }
#undef GI
}

extern "C" void kernel_launch(void* const* d_in, const int* in_sizes, int n_in,
                              void* d_out, int out_size, void* d_ws, size_t ws_size,
                              hipStream_t stream) {
    // setup_inputs order: 0:x(unused) 1:yl 2:yh 3:W_ode 4:b_ode 5:W_ih0 6:W_hh0
    // 7:b_ih0 8:b_hh0 9:W_ih1 10:W_hh1 11:b_ih1 12:b_hh1 13:W1 14:b1 15:W2 16:b2
    const float* yl   = (const float*)d_in[1];
    const float* yh   = (const float*)d_in[2];
    const float* Wode = (const float*)d_in[3];
    const float* bode = (const float*)d_in[4];
    const float* Wih0 = (const float*)d_in[5];
    const float* Whh0 = (const float*)d_in[6];
    const float* bih0 = (const float*)d_in[7];
    const float* bhh0 = (const float*)d_in[8];
    const float* Wih1 = (const float*)d_in[9];
    const float* Whh1 = (const float*)d_in[10];
    const float* bih1 = (const float*)d_in[11];
    const float* bhh1 = (const float*)d_in[12];
    const float* W1v  = (const float*)d_in[13];
    const float* b1v  = (const float*)d_in[14];
    const float* W2v  = (const float*)d_in[15];
    const float* b2v  = (const float*)d_in[16];

    ode_forecaster<<<dim3(NBLK), dim3(NTHR), 0, stream>>>(
        yl, yh, Wode, bode, Wih0, Whh0, bih0, bhh0,
        Wih1, Whh1, bih1, bhh1, W1v, b1v, W2v, b2v,
        (float*)d_out, (uint2*)d_ws);
}